// Round 7
// baseline (61.386 us; speedup 1.0000x reference)
//
#include <hip/hip_runtime.h>
#include <hip/hip_cooperative_groups.h>

typedef __attribute__((ext_vector_type(8))) short bf16x8;
typedef __attribute__((ext_vector_type(4))) float f32x4;

constexpr int NCH = 18;     // 32-k chunks per K-quarter (K = 2304 symmetrized)

__device__ __forceinline__ unsigned short bf_rne(float f) {
  unsigned u = __float_as_uint(f);
  return (unsigned short)((u + 0x7fffu + ((u >> 16) & 1u)) >> 16);
}

// symmetrize+pack one Wp element (fragment-linear layout, verified r5):
// e = ((kq*18 + j)*2048) + nt*512 + (q*16+r16)*8 + el
// holds W_sym[o = nt*16+r16][k = kq*576 + j*32 + q*8 + el]
__device__ __forceinline__ void wprep_one(const float* __restrict__ W,
                                          unsigned short* __restrict__ Wp, int e) {
  int c = e & 2047;
  int t2 = e >> 11;            // kq*18 + j
  int kq = t2 / 18;
  int j = t2 - kq * 18;
  int nt = c >> 9;
  int q = (c >> 7) & 3;
  int r16 = (c >> 3) & 15;
  int el = c & 7;
  int o = nt * 16 + r16;
  int kl = j * 32 + q * 8 + el;
  int jblk = kl >> 6, i = kl & 63;
  int run1 = 8 - kq;
  int G, F;
  if (jblk < run1) { G = 7 - kq; F = jblk; } else { G = kq; F = jblk - run1; }
  int f = F * 8 + (i >> 3), g = G * 8 + (i & 7);
  float v = W[o * 4096 + f * 64 + g];
  if (F != G) v += W[o * 4096 + g * 64 + f];
  Wp[e] = bf_rne(v);
}

// xT swizzle: q-dependent bit-4 flip -> in-loop xf reads spread across both
// 16-bank halves (2-way = free); bijective per row.
__device__ __forceinline__ int xidx(int row, int px) {
  return row * 128 + (px ^ row ^ ((row & 3) << 4));
}

// ---- single fused cooperative kernel: 256 blocks x 512 thr (1 block/CU) ----
// phase 1: pack Wp (each block 576 elems) | grid.sync | phase 2: bilinear MFMA
__global__ __launch_bounds__(512, 2) void fused_kernel(const float* __restrict__ x,
                                                       const float* __restrict__ W,
                                                       unsigned short* __restrict__ Wp,
                                                       float* __restrict__ out) {
  __shared__ float xT[8192];                 // [f 64][px 128] swizzled (32 KB)
  __shared__ alignas(16) float red[16384];   // epilogue reduction (64 KB)

  const int t = threadIdx.x;
  const int lane = t & 63;
  const int wv = t >> 6;        // 0..7
  const int kq = wv & 3;        // K quarter
  const int ph = wv >> 2;       // pixel half
  const int q = lane >> 4;
  const int r16 = lane & 15;
  const int pxbase = blockIdx.x * 128;

  // issue x-tile loads first (latency hides under wprep's scattered reads)
  const float* xsrc = x + (long)pxbase * 64;
  float4 xv[4];
#pragma unroll
  for (int c = 0; c < 4; ++c)
    xv[c] = *reinterpret_cast<const float4*>(xsrc + (c * 512 + t) * 4);

  // ---- phase 1: this block's share of Wp (576 elems = 512 + 64) ----
  {
    int base = blockIdx.x * 576;
    wprep_one(W, Wp, base + t);
    if (t < 64) wprep_one(W, Wp, base + 512 + t);
  }

  // x tile -> xT (transposed, swizzled)
#pragma unroll
  for (int c = 0; c < 4; ++c) {
    int e4 = c * 512 + t;
    int px = e4 >> 4;            // 0..127
    int f0 = (e4 & 15) * 4;
    xT[xidx(f0 + 0, px)] = xv[c].x;
    xT[xidx(f0 + 1, px)] = xv[c].y;
    xT[xidx(f0 + 2, px)] = xv[c].z;
    xT[xidx(f0 + 3, px)] = xv[c].w;
  }

  cooperative_groups::this_grid().sync();   // Wp + xT ready everywhere

  // ---- phase 2: wave (ph,kq) computes 64 px x 64 o over its K quarter ----
  const char* wsrc = reinterpret_cast<const char*>(Wp) + kq * 73728 + lane * 16;
  bf16x8 bufs[4][4];
  auto loadB = [&](int j, int slot) {
#pragma unroll
    for (int nt = 0; nt < 4; ++nt)
      bufs[slot][nt] = *reinterpret_cast<const bf16x8*>(wsrc + j * 4096 + nt * 1024);
  };
  loadB(0, 0); loadB(1, 1); loadB(2, 2);

  float xg[4][8];
  auto load_xg = [&](int G) {
#pragma unroll
    for (int m = 0; m < 4; ++m) {
      int px = ph * 64 + m * 16 + r16;
#pragma unroll
      for (int b = 0; b < 8; ++b)
        xg[m][b] = xT[xidx(G * 8 + b, px)];
    }
  };
  const int run1 = 8 - kq;
  load_xg(7 - kq);

  f32x4 acc[4][4] = {};   // [m: 4x16 px][nt: 4x16 o]

#pragma unroll
  for (int j = 0; j < NCH; ++j) {
    if (j + 3 < NCH) loadB(j + 3, (j + 3) & 3);   // issue-at-top: lead = 3 bodies
    if (j == 2 * run1) load_xg(kq);               // wave-uniform G-run switch
    const int s = j & 1;
    const int blk = j >> 1;
    const int F = (blk < run1) ? blk : blk - run1;
    const int row = F * 8 + s * 4 + q;
    const int slot = j & 3;
    bf16x8 afr[4];
#pragma unroll
    for (int m = 0; m < 4; ++m) {
      float xf = xT[xidx(row, ph * 64 + m * 16 + r16)];
      union { unsigned u[4]; bf16x8 v; } pk;
#pragma unroll
      for (int i = 0; i < 4; ++i) {
        unsigned p0 = __float_as_uint(xf * xg[m][2 * i]);
        unsigned p1 = __float_as_uint(xf * xg[m][2 * i + 1]);
        pk.u[i] = __builtin_amdgcn_perm(p1, p0, 0x07060302u);   // truncate-pack 2x bf16
      }
      afr[m] = pk.v;
    }
#pragma unroll
    for (int nt = 0; nt < 4; ++nt)
#pragma unroll
      for (int m = 0; m < 4; ++m)
        acc[m][nt] = __builtin_amdgcn_mfma_f32_16x16x32_bf16(afr[m], bufs[slot][nt],
                                                             acc[m][nt], 0, 0, 0);
  }

  // ---- cross-kq reduction (r5 structure, verified): 2 rounds of m-pairs ----
#pragma unroll
  for (int r = 0; r < 2; ++r) {
    if (r) __syncthreads();
#pragma unroll
    for (int mm = 0; mm < 2; ++mm)
#pragma unroll
      for (int nt = 0; nt < 2 * 2; ++nt)
        *reinterpret_cast<f32x4*>(red + ((ph * 2 + mm) * 4 + kq) * 1024 +
                                  (nt * 16 + r16) * 16 + q * 4) = acc[2 * r + mm][nt];
    __syncthreads();
    {
      const int mm2 = kq >> 1;
      const int h = kq & 1;
      const float* base = red + (ph * 2 + mm2) * 4 * 1024;
#pragma unroll
      for (int nh = 0; nh < 2; ++nh) {
        int nt = h * 2 + nh;
        int off = (nt * 16 + r16) * 16 + q * 4;
        f32x4 ssum = *reinterpret_cast<const f32x4*>(base + off);
#pragma unroll
        for (int w = 1; w < 4; ++w)
          ssum += *reinterpret_cast<const f32x4*>(base + w * 1024 + off);
        long prow = pxbase + ph * 64 + (2 * r + mm2) * 16 + q * 4;   // D: row=q*4+b, col=r16
#pragma unroll
        for (int b = 0; b < 4; ++b)
          out[(prow + b) * 64 + nt * 16 + r16] = ssum[b];
      }
    }
  }
}

extern "C" void kernel_launch(void* const* d_in, const int* in_sizes, int n_in,
                              void* d_out, int out_size, void* d_ws, size_t ws_size,
                              hipStream_t stream) {
  const float* x = (const float*)d_in[0];
  const float* W = (const float*)d_in[1];
  float* out = (float*)d_out;
  unsigned short* Wp = (unsigned short*)d_ws;   // 288 KB packed fragment-linear bf16 W

  void* args[] = {(void*)&x, (void*)&W, (void*)&Wp, (void*)&out};
  hipLaunchCooperativeKernel((const void*)fused_kernel, dim3(256), dim3(512),
                             args, 0, stream);
}

// Round 8
// 41.844 us; speedup vs baseline: 1.4670x; 1.4670x over previous
//
#include <hip/hip_runtime.h>

typedef __attribute__((ext_vector_type(8))) short bf16x8;
typedef __attribute__((ext_vector_type(4))) float f32x4;

constexpr int NCH = 18;     // 32-k chunks per K-quarter (K = 2304 symmetrized)

__device__ __forceinline__ unsigned short bf_rne(float f) {
  unsigned u = __float_as_uint(f);
  return (unsigned short)((u + 0x7fffu + ((u >> 16) & 1u)) >> 16);
}

// ---- prepass: symmetrize + pack W fragment-linear (verified r5) ----
// e = (kq*18 + j)*2048 + nt*512 + (q*16+r16)*8 + el
// holds W_sym[o = nt*16+r16][k = kq*576 + j*32 + q*8 + el]
__global__ __launch_bounds__(256) void wprep_kernel(const float* __restrict__ W,
                                                    unsigned short* __restrict__ Wp) {
  int e = blockIdx.x * 256 + threadIdx.x;   // 576*256 = 147456
  int c = e & 2047;
  int t2 = e >> 11;
  int kq = t2 / 18;
  int j = t2 - kq * 18;
  int nt = c >> 9;
  int q = (c >> 7) & 3;
  int r16 = (c >> 3) & 15;
  int el = c & 7;
  int o = nt * 16 + r16;
  int kl = j * 32 + q * 8 + el;
  int jblk = kl >> 6, i = kl & 63;
  int run1 = 8 - kq;
  int G, F;
  if (jblk < run1) { G = 7 - kq; F = jblk; } else { G = kq; F = jblk - run1; }
  int f = F * 8 + (i >> 3), g = G * 8 + (i & 7);
  float v = W[o * 4096 + f * 64 + g];
  if (F != G) v += W[o * 4096 + g * 64 + f];
  Wp[e] = bf_rne(v);
}

// ---- main quad: 256 blocks x 512 thr (8 waves = 2 ph x 4 kq), r5 structure ----
// B streamed to a 4-slot register ring, issue-at-top (lead = 3 bodies).
__global__ __launch_bounds__(512, 2) void quad_kernel(const float* __restrict__ x,
                                                      const unsigned short* __restrict__ Wp,
                                                      float* __restrict__ out) {
  __shared__ float xT[8192];                 // [f 64][px 128], word = f*128 + (px^f)
  __shared__ alignas(16) float red[16384];   // 16 regions x 4 KB

  const int t = threadIdx.x;
  const int lane = t & 63;
  const int wv = t >> 6;        // 0..7
  const int kq = wv & 3;        // K quarter
  const int ph = wv >> 2;       // pixel half
  const int q = lane >> 4;
  const int r16 = lane & 15;
  const int pxbase = blockIdx.x * 128;

  const char* wsrc = reinterpret_cast<const char*>(Wp) + kq * 73728 + lane * 16;

  bf16x8 bufs[4][4];
  auto loadB = [&](int j, int slot) {
#pragma unroll
    for (int nt = 0; nt < 4; ++nt)
      bufs[slot][nt] = *reinterpret_cast<const bf16x8*>(wsrc + j * 4096 + nt * 1024);
  };
  loadB(0, 0); loadB(1, 1); loadB(2, 2);

  // x tile -> xT (transposed, XOR word-swizzle; verified r3-r5)
  {
    const float* xg_ = x + (long)pxbase * 64;
#pragma unroll
    for (int c = 0; c < 4; ++c) {
      int e4 = c * 512 + t;
      int px = e4 >> 4;            // 0..127
      int f0 = (e4 & 15) * 4;
      float4 v = *reinterpret_cast<const float4*>(xg_ + e4 * 4);
      xT[(f0 + 0) * 128 + (px ^ (f0 + 0))] = v.x;
      xT[(f0 + 1) * 128 + (px ^ (f0 + 1))] = v.y;
      xT[(f0 + 2) * 128 + (px ^ (f0 + 2))] = v.z;
      xT[(f0 + 3) * 128 + (px ^ (f0 + 3))] = v.w;
    }
  }
  __syncthreads();

  float xg[4][8];
  auto load_xg = [&](int G) {
#pragma unroll
    for (int m = 0; m < 4; ++m) {
      int px = ph * 64 + m * 16 + r16;
#pragma unroll
      for (int b = 0; b < 8; ++b) {
        int row = G * 8 + b;
        xg[m][b] = xT[row * 128 + (px ^ row)];
      }
    }
  };
  const int run1 = 8 - kq;
  load_xg(7 - kq);

  f32x4 acc[4][4] = {};   // [m: 4x16 px][nt: 4x16 o]

#pragma unroll
  for (int j = 0; j < NCH; ++j) {
    if (j + 3 < NCH) loadB(j + 3, (j + 3) & 3);   // issue-at-top, lead = 3 bodies
    if (j == 2 * run1) load_xg(kq);               // wave-uniform G-run switch
    const int s = j & 1;
    const int blk = j >> 1;
    const int F = (blk < run1) ? blk : blk - run1;
    const int row = F * 8 + s * 4 + q;
    const int slot = j & 3;
    bf16x8 afr[4];
#pragma unroll
    for (int m = 0; m < 4; ++m) {
      float xf = xT[row * 128 + ((ph * 64 + m * 16 + r16) ^ row)];
      union { unsigned u[4]; bf16x8 v; } pk;
#pragma unroll
      for (int i = 0; i < 4; ++i) {
        unsigned p0 = __float_as_uint(xf * xg[m][2 * i]);
        unsigned p1 = __float_as_uint(xf * xg[m][2 * i + 1]);
        pk.u[i] = __builtin_amdgcn_perm(p1, p0, 0x07060302u);   // truncate-pack 2x bf16
      }
      afr[m] = pk.v;
    }
#pragma unroll
    for (int nt = 0; nt < 4; ++nt)
#pragma unroll
      for (int m = 0; m < 4; ++m)
        acc[m][nt] = __builtin_amdgcn_mfma_f32_16x16x32_bf16(afr[m], bufs[slot][nt],
                                                             acc[m][nt], 0, 0, 0);
  }

  // ---- cross-kq reduction (verified r5): 2 rounds of m-pairs ----
#pragma unroll
  for (int r = 0; r < 2; ++r) {
    if (r) __syncthreads();
#pragma unroll
    for (int mm = 0; mm < 2; ++mm)
#pragma unroll
      for (int nt = 0; nt < 4; ++nt)
        *reinterpret_cast<f32x4*>(red + ((ph * 2 + mm) * 4 + kq) * 1024 +
                                  (nt * 16 + r16) * 16 + q * 4) = acc[2 * r + mm][nt];
    __syncthreads();
    {
      const int mm2 = kq >> 1;
      const int h = kq & 1;
      const float* base = red + (ph * 2 + mm2) * 4 * 1024;
#pragma unroll
      for (int nh = 0; nh < 2; ++nh) {
        int nt = h * 2 + nh;
        int off = (nt * 16 + r16) * 16 + q * 4;
        f32x4 ssum = *reinterpret_cast<const f32x4*>(base + off);
#pragma unroll
        for (int w = 1; w < 4; ++w)
          ssum += *reinterpret_cast<const f32x4*>(base + w * 1024 + off);
        long prow = pxbase + ph * 64 + (2 * r + mm2) * 16 + q * 4;   // D: row=q*4+b, col=r16
#pragma unroll
        for (int b = 0; b < 4; ++b)
          out[(prow + b) * 64 + nt * 16 + r16] = ssum[b];
      }
    }
  }
}

extern "C" void kernel_launch(void* const* d_in, const int* in_sizes, int n_in,
                              void* d_out, int out_size, void* d_ws, size_t ws_size,
                              hipStream_t stream) {
  const float* x = (const float*)d_in[0];
  const float* W = (const float*)d_in[1];
  float* out = (float*)d_out;
  unsigned short* Wp = (unsigned short*)d_ws;   // 288 KB packed fragment-linear bf16 W

  hipLaunchKernelGGL(wprep_kernel, dim3(576), dim3(256), 0, stream, W, Wp);
  // PROBE round: quad launched TWICE (deterministic, identical output).
  // dur_us - 24.1 ~= marginal warm cost of one quad dispatch.
  hipLaunchKernelGGL(quad_kernel, dim3(256), dim3(512), 0, stream, x, Wp, out);
  hipLaunchKernelGGL(quad_kernel, dim3(256), dim3(512), 0, stream, x, Wp, out);
}

// Round 9
// 34.661 us; speedup vs baseline: 1.7711x; 1.2073x over previous
//
#include <hip/hip_runtime.h>

typedef __attribute__((ext_vector_type(8))) short bf16x8;
typedef __attribute__((ext_vector_type(4))) float f32x4;

constexpr int NCH = 18;     // 32-k chunks per K-quarter (K = 2304 symmetrized)

__device__ __forceinline__ unsigned short bf_rne(float f) {
  unsigned u = __float_as_uint(f);
  return (unsigned short)((u + 0x7fffu + ((u >> 16) & 1u)) >> 16);
}

// ---- prepass: symmetrize + pack W fragment-linear (verbatim r8, verified) ----
// e = (kq*18 + j)*2048 + nt*512 + (q*16+r16)*8 + el
// holds W_sym[o = nt*16+r16][k = kq*576 + j*32 + q*8 + el]
__global__ __launch_bounds__(256) void wprep_kernel(const float* __restrict__ W,
                                                    unsigned short* __restrict__ Wp) {
  int e = blockIdx.x * 256 + threadIdx.x;   // 576*256 = 147456
  int c = e & 2047;
  int t2 = e >> 11;
  int kq = t2 / 18;
  int j = t2 - kq * 18;
  int nt = c >> 9;
  int q = (c >> 7) & 3;
  int r16 = (c >> 3) & 15;
  int el = c & 7;
  int o = nt * 16 + r16;
  int kl = j * 32 + q * 8 + el;
  int jblk = kl >> 6, i = kl & 63;
  int run1 = 8 - kq;
  int G, F;
  if (jblk < run1) { G = 7 - kq; F = jblk; } else { G = kq; F = jblk - run1; }
  int f = F * 8 + (i >> 3), g = G * 8 + (i & 7);
  float v = W[o * 4096 + f * 64 + g];
  if (F != G) v += W[o * 4096 + g * 64 + f];
  Wp[e] = bf_rne(v);
}

// xT swizzle: px ^ row spreads r16 lanes; ^((row&3)<<4) spreads q-groups across
// bank halves (2-way = free). Bijective within each row.
__device__ __forceinline__ int xidx(int row, int px) {
  return row * 128 + (px ^ row ^ ((row & 3) << 4));
}

// ---- main quad: 256 blocks x 1024 thr = 16 waves (4 kq x 4 pq), 128 px/block ----
// 4 waves/SIMD (VGPR<=128, LDS 64 KB) for latency hiding; per-wave 32px x 64o.
__global__ __launch_bounds__(1024, 4) void quad_kernel(const float* __restrict__ x,
                                                       const unsigned short* __restrict__ Wp,
                                                       float* __restrict__ out) {
  __shared__ alignas(16) char smem[65536];   // [0,32K): xT | epilogue: 64 KB red
  float* xT = reinterpret_cast<float*>(smem);

  const int t = threadIdx.x;
  const int lane = t & 63;
  const int wv = t >> 6;        // 0..15
  const int kq = wv & 3;        // K quarter
  const int pq = wv >> 2;       // px quarter (32 px)
  const int q = lane >> 4;
  const int r16 = lane & 15;
  const int pxbase = blockIdx.x * 128;

  const char* wsrc = reinterpret_cast<const char*>(Wp) + kq * 73728 + lane * 16;

  bf16x8 bufs[3][4];
  auto loadB = [&](int j, int slot) {
#pragma unroll
    for (int nt = 0; nt < 4; ++nt)
      bufs[slot][nt] = *reinterpret_cast<const bf16x8*>(wsrc + j * 4096 + nt * 1024);
  };
  loadB(0, 0);
  loadB(1, 1);

  // x tile -> xT (transposed, swizzled); 1024 thr x 2 float4
  {
    const float* xg_ = x + (long)pxbase * 64;
#pragma unroll
    for (int c = 0; c < 2; ++c) {
      int e4 = c * 1024 + t;
      int px = e4 >> 4;            // 0..127
      int f0 = (e4 & 15) * 4;
      float4 v = *reinterpret_cast<const float4*>(xg_ + e4 * 4);
      xT[xidx(f0 + 0, px)] = v.x;
      xT[xidx(f0 + 1, px)] = v.y;
      xT[xidx(f0 + 2, px)] = v.z;
      xT[xidx(f0 + 3, px)] = v.w;
    }
  }
  __syncthreads();

  float xg[2][8];
  auto load_xg = [&](int G) {
#pragma unroll
    for (int m = 0; m < 2; ++m) {
      int px = pq * 32 + m * 16 + r16;
#pragma unroll
      for (int b = 0; b < 8; ++b)
        xg[m][b] = xT[xidx(G * 8 + b, px)];   // broadcast across q-groups (free)
    }
  };
  const int run1 = 8 - kq;
  load_xg(7 - kq);

  f32x4 acc[2][4] = {};   // [m: 2x16 px][nt: 4x16 o]

#pragma unroll
  for (int j = 0; j < NCH; ++j) {
    if (j + 2 < NCH) loadB(j + 2, (j + 2) % 3);   // ring lead = 2 bodies
    if (j == 2 * run1) load_xg(kq);               // wave-uniform G-run switch
    const int s = j & 1;
    const int blk = j >> 1;
    const int F = (blk < run1) ? blk : blk - run1;
    const int row = F * 8 + s * 4 + q;
    const int slot = j % 3;
    bf16x8 afr[2];
#pragma unroll
    for (int m = 0; m < 2; ++m) {
      float xf = xT[xidx(row, pq * 32 + m * 16 + r16)];
      union { unsigned u[4]; bf16x8 v; } pk;
#pragma unroll
      for (int i = 0; i < 4; ++i) {
        unsigned p0 = __float_as_uint(xf * xg[m][2 * i]);
        unsigned p1 = __float_as_uint(xf * xg[m][2 * i + 1]);
        pk.u[i] = __builtin_amdgcn_perm(p1, p0, 0x07060302u);   // truncate-pack 2x bf16
      }
      afr[m] = pk.v;
    }
#pragma unroll
    for (int nt = 0; nt < 4; ++nt)
#pragma unroll
      for (int m = 0; m < 2; ++m)
        acc[m][nt] = __builtin_amdgcn_mfma_f32_16x16x32_bf16(afr[m], bufs[slot][nt],
                                                             acc[m][nt], 0, 0, 0);
  }

  // ---- epilogue: 2-step kq reduction tree through 64 KB red ----
  // region(m, kw, pq) = ((m*2+kw)*4 + pq) * 1024 floats, layout [o 64][px 16]
  __syncthreads();
  float* red = reinterpret_cast<float*>(smem);
  auto wr_region = [&](int kw) {
#pragma unroll
    for (int m = 0; m < 2; ++m)
#pragma unroll
      for (int nt = 0; nt < 4; ++nt)
        *reinterpret_cast<f32x4*>(red + ((m * 2 + kw) * 4 + pq) * 1024 +
                                  (nt * 16 + r16) * 16 + q * 4) = acc[m][nt];
  };
  auto rd_region = [&](int kw) {
#pragma unroll
    for (int m = 0; m < 2; ++m)
#pragma unroll
      for (int nt = 0; nt < 4; ++nt)
        acc[m][nt] += *reinterpret_cast<const f32x4*>(red + ((m * 2 + kw) * 4 + pq) * 1024 +
                                                      (nt * 16 + r16) * 16 + q * 4);
  };

  if (kq & 1) wr_region(kq >> 1);        // kq 1 -> slot 0, kq 3 -> slot 1
  __syncthreads();
  if (!(kq & 1)) rd_region(kq >> 1);     // kq 0 += kq1, kq 2 += kq3
  __syncthreads();
  if (kq == 2) wr_region(1);             // partial (kq2+kq3) -> slot 1
  __syncthreads();
  if (kq == 0) {
    rd_region(1);                        // full sum
    // D layout: row = q*4 + b, col = r16 (verified r1-r8); coalesced 256B stores
#pragma unroll
    for (int m = 0; m < 2; ++m)
#pragma unroll
      for (int nt = 0; nt < 4; ++nt)
#pragma unroll
        for (int b = 0; b < 4; ++b)
          out[(long)(pxbase + pq * 32 + m * 16 + q * 4 + b) * 64 + nt * 16 + r16] =
              acc[m][nt][b];
  }
}

extern "C" void kernel_launch(void* const* d_in, const int* in_sizes, int n_in,
                              void* d_out, int out_size, void* d_ws, size_t ws_size,
                              hipStream_t stream) {
  const float* x = (const float*)d_in[0];
  const float* W = (const float*)d_in[1];
  float* out = (float*)d_out;
  unsigned short* Wp = (unsigned short*)d_ws;   // 288 KB packed fragment-linear bf16 W

  hipLaunchKernelGGL(wprep_kernel, dim3(576), dim3(256), 0, stream, W, Wp);
  hipLaunchKernelGGL(quad_kernel, dim3(256), dim3(1024), 0, stream, x, Wp, out);
}